// Round 18
// baseline (56.121 us; speedup 1.0000x reference)
//
#include <hip/hip_runtime.h>
#include <hip/hip_bf16.h>

// Problem constants
#define HEIGHT 480
#define WIDTH  640
#define IN_CH  6
#define CIN    8      // p, 1-p, 6 features
#define COUT   32
#define BATCH  8
#define NPTS   16384
#define NPTOT  (BATCH * NPTS)          // 131072 = 2^17
// Padded grid: rows 0..482 (point rows 1..481), cols 0..642 (point cols 1..641)
#define GH 483
#define GW 643
#define NCELLS ((size_t)BATCH * GH * GW)   // 2,484,552 cells
#define NW64   38824                       // ceil(NCELLS/64)=38822 +guard, even

typedef float f32x2 __attribute__((ext_vector_type(2)));  // maps to v_pk_fma_f32

// grid layout: [b][gy][gx][cin], cin contiguous (32B per cell, 32B-aligned)
__device__ __forceinline__ size_t cell_idx(int b, int gy, int gx) {
    return ((size_t)b * GH + gy) * GW + gx;
}

__device__ __forceinline__ void point_cell(const float4 q, int point,
                                           int& b, int& gy, int& gx) {
    gy = (int)rintf(q.z * (float)HEIGHT) + 1;   // padded coord
    gx = (int)rintf(q.y * (float)WIDTH) + 1;
    b  = point >> 14;                           // NPTS = 16384
}

// Phase 0: zero counter (16B header) + occ bitmask, contiguous uint4 sweep.
__global__ void zero_masks_kernel(uint4* __restrict__ m4, int n4) {
    int i = blockIdx.x * blockDim.x + threadIdx.x;
    if (i < n4) m4[i] = make_uint4(0u, 0u, 0u, 0u);
}

// Phase 1 (merged count+write): per point, claim the cell via u64 atomicOr.
// Owner (bit was clear, ~97%): plain 32B store - overwrites stale data, no
// zeroing needed. Collider: append (ci, vals) to the overflow list; the fix
// kernel adds them AFTER the dispatch boundary (so owner stores have landed).
__global__ void scatter_kernel(const float4* __restrict__ xytp,
                               const float*  __restrict__ feats,
                               unsigned long long* __restrict__ occ,
                               unsigned int* __restrict__ n_over,
                               unsigned int* __restrict__ over_idx,
                               float4* __restrict__ over_val,
                               float* __restrict__ grid) {
    int point = blockIdx.x * blockDim.x + threadIdx.x;
    if (point >= NPTOT) return;
    float4 q = xytp[point];
    int b, gy, gx;
    point_cell(q, point, b, gy, gx);
    size_t ci = cell_idx(b, gy, gx);

    const float* f = feats + (size_t)point * IN_CH;
    float v0 = q.w, v1 = 1.0f - q.w;
    float f0 = f[0], f1 = f[1], f2 = f[2], f3 = f[3], f4 = f[4], f5 = f[5];

    unsigned long long bit = 1ull << (ci & 63);
    unsigned long long old = atomicOr(&occ[ci >> 6], bit);
    if (!(old & bit)) {
        // Owner: plain stores (keep lines in L2 for conv).
        float* cell = grid + (ci << 3);
        *(float4*)(cell)     = make_float4(v0, v1, f0, f1);
        *(float4*)(cell + 4) = make_float4(f2, f3, f4, f5);
    } else {
        // Collider (~3%): append to overflow.
        unsigned int slot = atomicAdd(n_over, 1u);
        over_idx[slot] = (unsigned int)ci;
        over_val[2 * slot]     = make_float4(v0, v1, f0, f1);
        over_val[2 * slot + 1] = make_float4(f2, f3, f4, f5);
    }
}

// Phase 2: fix-up - atomic-add overflow entries onto the owner-stored cells.
// Grid-stride over the actual count (~4K entries).
__global__ void fix_kernel(const unsigned int* __restrict__ n_over,
                           const unsigned int* __restrict__ over_idx,
                           const float4* __restrict__ over_val,
                           float* __restrict__ grid) {
    unsigned int n = *n_over;
    unsigned int stride = gridDim.x * blockDim.x;
    for (unsigned int i = blockIdx.x * blockDim.x + threadIdx.x; i < n; i += stride) {
        size_t ci = over_idx[i];
        float4 a = over_val[2 * i];
        float4 d = over_val[2 * i + 1];
        float* cell = grid + (ci << 3);
        unsafeAtomicAdd(cell + 0, a.x);
        unsafeAtomicAdd(cell + 1, a.y);
        unsafeAtomicAdd(cell + 2, a.z);
        unsafeAtomicAdd(cell + 3, a.w);
        unsafeAtomicAdd(cell + 4, d.x);
        unsafeAtomicAdd(cell + 5, d.y);
        unsafeAtomicAdd(cell + 6, d.z);
        unsafeAtomicAdd(cell + 7, d.w);
    }
}

// Phase 3: 1 thread per point. u64 occ-row loads, loads-batched masked gather,
// packed-FMA accumulation (v_pk_fma_f32).
__global__ void __launch_bounds__(256)
conv_gather_kernel(const float4* __restrict__ xytp,
                   const float*  __restrict__ grid,
                   const unsigned long long* __restrict__ occ,
                   const float*  __restrict__ W,     // [3][3][8][32]
                   const float*  __restrict__ bias,  // [32]
                   float* __restrict__ out) {
    int point = blockIdx.x * blockDim.x + threadIdx.x;
    if (point >= NPTOT) return;
    float4 q = xytp[point];
    int b, gy, gx;
    point_cell(q, point, b, gy, gx);
    size_t center  = cell_idx(b, gy, gx);
    size_t base_ci = center - GW - 1;   // padded window top-left

    // Occupancy bits: one aligned u64 load per row (straddle load ~3%/row).
    unsigned int occ9 = 0;
#pragma unroll
    for (int ky = 0; ky < 3; ++ky) {
        size_t ci_row = base_ci + (size_t)ky * GW;
        size_t w  = ci_row >> 6;
        int    sh = (int)(ci_row & 63);
        unsigned long long v = occ[w] >> sh;
        if (sh >= 62) v |= occ[w + 1] << (64 - sh);
        occ9 |= ((unsigned int)v & 7u) << (ky * 3);
    }

    // Loads-only masked pass (all occupied-cell loads in one latency window).
    float4 g0[9], g1[9];
#pragma unroll
    for (int k = 0; k < 9; ++k) {
        if (occ9 & (1u << k)) {
            size_t ci = base_ci + (size_t)(k / 3) * GW + (k % 3);
            const float* cell = grid + (ci << 3);
            g0[k] = *(const float4*)(cell);
            g1[k] = *(const float4*)(cell + 4);
        }
    }

    // Masked packed-FMA pass: acc as 16 x f32x2.
    const f32x2* bias2 = (const f32x2*)bias;
    f32x2 acc[16];
#pragma unroll
    for (int c = 0; c < 16; ++c) acc[c] = bias2[c];

#pragma unroll
    for (int k = 0; k < 9; ++k) {
        if (occ9 & (1u << k)) {
            float4 a = g0[k], d = g1[k];
            float gv[CIN] = {a.x, a.y, a.z, a.w, d.x, d.y, d.z, d.w};
            const float* wp = W + k * CIN * COUT;
#pragma unroll
            for (int ci2 = 0; ci2 < CIN; ++ci2) {
                const f32x2* w2 = (const f32x2*)(wp + ci2 * COUT);
                f32x2 gg = {gv[ci2], gv[ci2]};
#pragma unroll
                for (int c = 0; c < 16; ++c) {
                    acc[c] = __builtin_elementwise_fma(gg, w2[c], acc[c]);
                }
            }
        }
    }

    float* o = out + (size_t)point * COUT;
#pragma unroll
    for (int c = 0; c < 8; ++c) {
        *(float4*)(o + c * 4) = make_float4(acc[2 * c].x, acc[2 * c].y,
                                            acc[2 * c + 1].x, acc[2 * c + 1].y);
    }
}

extern "C" void kernel_launch(void* const* d_in, const int* in_sizes, int n_in,
                              void* d_out, int out_size, void* d_ws, size_t ws_size,
                              hipStream_t stream) {
    const float4* xytp  = (const float4*)d_in[0];   // (8,16384,4)
    const float*  feats = (const float*)d_in[1];    // (8,16384,6)
    const float*  W     = (const float*)d_in[2];    // (3,3,8,32)
    const float*  bias  = (const float*)d_in[3];    // (32,)
    float* out = (float*)d_out;                     // (8,16384,32)

    // Workspace layout:
    //   grid     : NCELLS*32 B                  (79.5 MB)
    //   header   : 16 B  (n_over counter + pad)
    //   occ      : NW64*8 B                     (310 KB)
    //   over_idx : NPTOT*4 B                    (512 KB)
    //   over_val : NPTOT*32 B                   (4 MB)
    float* grid = (float*)d_ws;
    const size_t grid_bytes = NCELLS * CIN * sizeof(float);
    char* p = (char*)d_ws + grid_bytes;
    unsigned int*       n_over   = (unsigned int*)p;
    unsigned long long* occ      = (unsigned long long*)(p + 16);
    unsigned int*       over_idx = (unsigned int*)(p + 16 + (size_t)NW64 * 8);
    float4*             over_val = (float4*)(p + 16 + (size_t)NW64 * 8 + (size_t)NPTOT * 4);
    (void)ws_size;

    const int blk = 256;
    const int nblk_pts = (NPTOT + blk - 1) / blk;   // 512

    // Zero header + occ in one sweep (16 + NW64*8 bytes, 16B-aligned).
    const int n4 = (int)((16 + (size_t)NW64 * 8) / 16);
    zero_masks_kernel<<<(n4 + blk - 1) / blk, blk, 0, stream>>>((uint4*)p, n4);

    scatter_kernel<<<nblk_pts, blk, 0, stream>>>(xytp, feats, occ, n_over,
                                                 over_idx, over_val, grid);

    fix_kernel<<<128, blk, 0, stream>>>(n_over, over_idx, over_val, grid);

    conv_gather_kernel<<<nblk_pts, blk, 0, stream>>>(xytp, grid, occ, W, bias, out);
}

// Round 19
// 39.576 us; speedup vs baseline: 1.4181x; 1.4181x over previous
//
#include <hip/hip_runtime.h>
#include <hip/hip_bf16.h>

// Problem constants
#define HEIGHT 480
#define WIDTH  640
#define IN_CH  6
#define CIN    8      // p, 1-p, 6 features
#define COUT   32
#define BATCH  8
#define NPTS   16384
#define NPTOT  (BATCH * NPTS)          // 131072 = 2^17
// Padded grid: rows 0..482 (point rows 1..481), cols 0..642 (point cols 1..641)
#define GH 483
#define GW 643
#define NCELLS ((size_t)BATCH * GH * GW)   // 2,484,552 cells
#define NW64   38824                       // ceil(NCELLS/64)=38822 +guard, even
#define SENTINEL 0xFFFFFFFFu

typedef float f32x2 __attribute__((ext_vector_type(2)));  // maps to v_pk_fma_f32

// grid layout: [b][gy][gx][cin], cin contiguous (32B per cell, 32B-aligned)
__device__ __forceinline__ size_t cell_idx(int b, int gy, int gx) {
    return ((size_t)b * GH + gy) * GW + gx;
}

__device__ __forceinline__ void point_cell(const float4 q, int point,
                                           int& b, int& gy, int& gx) {
    gy = (int)rintf(q.z * (float)HEIGHT) + 1;   // padded coord
    gx = (int)rintf(q.y * (float)WIDTH) + 1;
    b  = point >> 14;                           // NPTS = 16384
}

// Phase 0: zero the occ bitmask (310 KB, contiguous uint4 sweep).
__global__ void zero_masks_kernel(uint4* __restrict__ m4, int n4) {
    int i = blockIdx.x * blockDim.x + threadIdx.x;
    if (i < n4) m4[i] = make_uint4(0u, 0u, 0u, 0u);
}

// Phase 1 (merged count+write): claim cell via u64 atomicOr.
// Owner (~97%): plain 32B store (overwrites stale data - no zeroing pass).
// Collider: record (ci, vals) in DENSE per-point slots - no shared counter,
// all slot stores coalesced. Everyone stores over_idx[point] (4B coalesced).
__global__ void scatter_kernel(const float4* __restrict__ xytp,
                               const float*  __restrict__ feats,
                               unsigned long long* __restrict__ occ,
                               unsigned int* __restrict__ over_idx,
                               float4* __restrict__ over_val,
                               float* __restrict__ grid) {
    int point = blockIdx.x * blockDim.x + threadIdx.x;
    if (point >= NPTOT) return;
    float4 q = xytp[point];
    int b, gy, gx;
    point_cell(q, point, b, gy, gx);
    size_t ci = cell_idx(b, gy, gx);

    const float* f = feats + (size_t)point * IN_CH;
    float v0 = q.w, v1 = 1.0f - q.w;
    float f0 = f[0], f1 = f[1], f2 = f[2], f3 = f[3], f4 = f[4], f5 = f[5];

    unsigned long long bit = 1ull << (ci & 63);
    unsigned long long old = atomicOr(&occ[ci >> 6], bit);
    bool collider = (old & bit) != 0ull;

    over_idx[point] = collider ? (unsigned int)ci : SENTINEL;  // coalesced

    if (!collider) {
        float* cell = grid + (ci << 3);
        *(float4*)(cell)     = make_float4(v0, v1, f0, f1);
        *(float4*)(cell + 4) = make_float4(f2, f3, f4, f5);
    } else {                                   // ~3%
        over_val[2 * point]     = make_float4(v0, v1, f0, f1);
        over_val[2 * point + 1] = make_float4(f2, f3, f4, f5);
    }
}

// Phase 2: fix-up - coalesced scan of the dense slots; ~4K valid entries do
// 8 HW atomics each onto owner-stored cells (dispatch boundary ordered).
__global__ void fix_kernel(const unsigned int* __restrict__ over_idx,
                           const float4* __restrict__ over_val,
                           float* __restrict__ grid) {
    int point = blockIdx.x * blockDim.x + threadIdx.x;
    if (point >= NPTOT) return;
    unsigned int ci32 = over_idx[point];
    if (ci32 == SENTINEL) return;
    size_t ci = ci32;
    float4 a = over_val[2 * point];
    float4 d = over_val[2 * point + 1];
    float* cell = grid + (ci << 3);
    unsafeAtomicAdd(cell + 0, a.x);
    unsafeAtomicAdd(cell + 1, a.y);
    unsafeAtomicAdd(cell + 2, a.z);
    unsafeAtomicAdd(cell + 3, a.w);
    unsafeAtomicAdd(cell + 4, d.x);
    unsafeAtomicAdd(cell + 5, d.y);
    unsafeAtomicAdd(cell + 6, d.z);
    unsafeAtomicAdd(cell + 7, d.w);
}

// Phase 3: 1 thread per point. u64 occ-row loads, loads-batched masked gather,
// packed-FMA accumulation (v_pk_fma_f32).
__global__ void __launch_bounds__(256)
conv_gather_kernel(const float4* __restrict__ xytp,
                   const float*  __restrict__ grid,
                   const unsigned long long* __restrict__ occ,
                   const float*  __restrict__ W,     // [3][3][8][32]
                   const float*  __restrict__ bias,  // [32]
                   float* __restrict__ out) {
    int point = blockIdx.x * blockDim.x + threadIdx.x;
    if (point >= NPTOT) return;
    float4 q = xytp[point];
    int b, gy, gx;
    point_cell(q, point, b, gy, gx);
    size_t center  = cell_idx(b, gy, gx);
    size_t base_ci = center - GW - 1;   // padded window top-left

    // Occupancy bits: one aligned u64 load per row (straddle load ~3%/row).
    unsigned int occ9 = 0;
#pragma unroll
    for (int ky = 0; ky < 3; ++ky) {
        size_t ci_row = base_ci + (size_t)ky * GW;
        size_t w  = ci_row >> 6;
        int    sh = (int)(ci_row & 63);
        unsigned long long v = occ[w] >> sh;
        if (sh >= 62) v |= occ[w + 1] << (64 - sh);
        occ9 |= ((unsigned int)v & 7u) << (ky * 3);
    }

    // Loads-only masked pass (all occupied-cell loads in one latency window).
    float4 g0[9], g1[9];
#pragma unroll
    for (int k = 0; k < 9; ++k) {
        if (occ9 & (1u << k)) {
            size_t ci = base_ci + (size_t)(k / 3) * GW + (k % 3);
            const float* cell = grid + (ci << 3);
            g0[k] = *(const float4*)(cell);
            g1[k] = *(const float4*)(cell + 4);
        }
    }

    // Masked packed-FMA pass: acc as 16 x f32x2.
    const f32x2* bias2 = (const f32x2*)bias;
    f32x2 acc[16];
#pragma unroll
    for (int c = 0; c < 16; ++c) acc[c] = bias2[c];

#pragma unroll
    for (int k = 0; k < 9; ++k) {
        if (occ9 & (1u << k)) {
            float4 a = g0[k], d = g1[k];
            float gv[CIN] = {a.x, a.y, a.z, a.w, d.x, d.y, d.z, d.w};
            const float* wp = W + k * CIN * COUT;
#pragma unroll
            for (int ci2 = 0; ci2 < CIN; ++ci2) {
                const f32x2* w2 = (const f32x2*)(wp + ci2 * COUT);
                f32x2 gg = {gv[ci2], gv[ci2]};
#pragma unroll
                for (int c = 0; c < 16; ++c) {
                    acc[c] = __builtin_elementwise_fma(gg, w2[c], acc[c]);
                }
            }
        }
    }

    float* o = out + (size_t)point * COUT;
#pragma unroll
    for (int c = 0; c < 8; ++c) {
        *(float4*)(o + c * 4) = make_float4(acc[2 * c].x, acc[2 * c].y,
                                            acc[2 * c + 1].x, acc[2 * c + 1].y);
    }
}

extern "C" void kernel_launch(void* const* d_in, const int* in_sizes, int n_in,
                              void* d_out, int out_size, void* d_ws, size_t ws_size,
                              hipStream_t stream) {
    const float4* xytp  = (const float4*)d_in[0];   // (8,16384,4)
    const float*  feats = (const float*)d_in[1];    // (8,16384,6)
    const float*  W     = (const float*)d_in[2];    // (3,3,8,32)
    const float*  bias  = (const float*)d_in[3];    // (32,)
    float* out = (float*)d_out;                     // (8,16384,32)

    // Workspace layout:
    //   grid     : NCELLS*32 B   (79.5 MB)
    //   occ      : NW64*8 B      (310 KB)
    //   over_idx : NPTOT*4 B     (512 KB)
    //   over_val : NPTOT*32 B    (4 MB)
    float* grid = (float*)d_ws;
    const size_t grid_bytes = NCELLS * CIN * sizeof(float);
    char* p = (char*)d_ws + grid_bytes;
    unsigned long long* occ      = (unsigned long long*)p;
    unsigned int*       over_idx = (unsigned int*)(p + (size_t)NW64 * 8);
    float4*             over_val = (float4*)(p + (size_t)NW64 * 8 + (size_t)NPTOT * 4);
    (void)ws_size;

    const int blk = 256;
    const int nblk_pts = (NPTOT + blk - 1) / blk;   // 512

    const int n4 = (int)(((size_t)NW64 * 8) / 16);  // 19,412 uint4
    zero_masks_kernel<<<(n4 + blk - 1) / blk, blk, 0, stream>>>((uint4*)occ, n4);

    scatter_kernel<<<nblk_pts, blk, 0, stream>>>(xytp, feats, occ,
                                                 over_idx, over_val, grid);

    fix_kernel<<<nblk_pts, blk, 0, stream>>>(over_idx, over_val, grid);

    conv_gather_kernel<<<nblk_pts, blk, 0, stream>>>(xytp, grid, occ, W, bias, out);
}